// Round 1
// baseline (308.885 us; speedup 1.0000x reference)
//
#include <hip/hip_runtime.h>
#include <hip/hip_bf16.h>
#include <cstdint>

#define BATCH   4096
#define IN_DIM  1024
#define OUT_DIM 1024
#define NEXP    16
#define KDIM    (NEXP * IN_DIM)   // 16384

typedef __bf16 bf16;
typedef __attribute__((ext_vector_type(8))) __bf16 bf16x8;
typedef __attribute__((ext_vector_type(4))) float  f32x4;

#define AS1 __attribute__((address_space(1)))
#define AS3 __attribute__((address_space(3)))

__device__ __forceinline__ void gld_lds16(const bf16* g, bf16* l) {
    __builtin_amdgcn_global_load_lds((const AS1 void*)g, (AS3 void*)l, 16, 0, 0);
}

// ---------------------------------------------------------------------------
// Pre-kernel 1: x fp32 [4096][1024] -> 512 pre-tiled swizzled bf16 LDS images.
// Tile (mblk 0..31, ks 0..15) = 128 rows x 64 k = 16 KB. Within a tile, byte
// f = m_loc*128 + sc*16 holds x[mblk*128+m_loc][ks*64 + (sc^(m_loc&7))*8 + j].
// ---------------------------------------------------------------------------
__global__ void convert_x_tiled(const float* __restrict__ x, bf16* __restrict__ xt) {
    int tile = blockIdx.x;                 // 512
    int mblk = tile >> 4, ks = tile & 15;
    int t = threadIdx.x;
#pragma unroll
    for (int r = 0; r < 4; r++) {
        int q = r * 256 + t;               // 16B chunk id, 0..1023
        int m_loc = q >> 3, sc = q & 7;
        int c = sc ^ (m_loc & 7);
        const float* src = x + (size_t)(mblk * 128 + m_loc) * IN_DIM + ks * 64 + c * 8;
        f32x4 a = *(const f32x4*)src;
        f32x4 b = *(const f32x4*)(src + 4);
        bf16x8 v;
#pragma unroll
        for (int j = 0; j < 4; j++) { v[j] = (bf16)a[j]; v[4 + j] = (bf16)b[j]; }
        *(bf16x8*)(xt + (size_t)tile * 8192 + q * 8) = v;
    }
}

// ---------------------------------------------------------------------------
// Pre-kernel 2: weight fp32 flat [16384][1024] -> 4096 pre-tiled transposed
// swizzled bf16 images. Tile (nblk 0..15, kstep 0..255) = 64 n x 64 k = 8 KB.
// Byte f = n_loc*128 + sc*16 holds W[k0 + (sc^(n_loc&7))*8 + j][n0+n_loc].
// Transpose goes through LDS so global reads AND writes stay coalesced.
// ---------------------------------------------------------------------------
__global__ void convert_w_tiled(const float* __restrict__ W, bf16* __restrict__ wt) {
    int tile = blockIdx.x;                 // 4096
    int kstep = tile & 255, nblk = tile >> 8;
    int k0 = kstep * 64, n0 = nblk * 64;
    int t = threadIdx.x;
    __shared__ float lt[64][65];           // lt[k_loc][n_loc], +1 pad
    int kl = t >> 4, cb = (t & 15) * 4;
#pragma unroll
    for (int r = 0; r < 4; r++) {
        int k = kl + r * 16;
        f32x4 v = *(const f32x4*)(W + (size_t)(k0 + k) * OUT_DIM + n0 + cb);
#pragma unroll
        for (int c = 0; c < 4; c++) lt[k][cb + c] = v[c];
    }
    __syncthreads();
#pragma unroll
    for (int r = 0; r < 2; r++) {
        int idx = r * 256 + t;             // 16B chunk id, 0..511
        int n_loc = idx >> 3, sc = idx & 7;
        int c = sc ^ (n_loc & 7);
        bf16x8 v;
#pragma unroll
        for (int j = 0; j < 8; j++) v[j] = (bf16)lt[c * 8 + j][n_loc];
        *(bf16x8*)(wt + (size_t)tile * 4096 + idx * 8) = v;
    }
}

// ---------------------------------------------------------------------------
// Main GEMM: out = relu(A' @ W' + cw@bias), A'[b,n*1024+i] = cw[b,n]*x[b,i].
// BM=128 BN=64 BK=64, 256 thr = 4 waves (2x2), 64x32 per wave, mfma 16x16x32.
// cw scaling deferred: per-expert partial acc, folded every 16 k-steps.
// Bias applied as one extra MFMA k-step (A=cw, B=bias, zero-padded to K=32).
// ---------------------------------------------------------------------------
__global__ __launch_bounds__(256, 2) void moe_gemm(
        const float* __restrict__ cw, const float* __restrict__ bias,
        const bf16* __restrict__ xt, const bf16* __restrict__ wt,
        float* __restrict__ out) {
    int nblk = blockIdx.x;                 // 16
    int mblk = blockIdx.y;                 // 32
    int m0 = mblk * 128, n0 = nblk * 64;
    int t = threadIdx.x;
    int lane = t & 63, w = t >> 6;
    int wm = w >> 1, wn = w & 1;
    int lq = lane >> 4, lr = lane & 15;

    __shared__ bf16 As[128 * 64];          // 16 KB, swizzled image
    __shared__ bf16 Bs[64 * 64];           // 8 KB, swizzled image
    __shared__ float cwS[128 * 17];        // 8.5 KB, padded (+1) for bank spread

    // stage cw rows for this M-panel into LDS (fully coalesced)
#pragma unroll
    for (int r = 0; r < 2; r++) {
        int idx = r * 256 + t;             // 512 float4 = 2048 floats
        f32x4 v = *(const f32x4*)(cw + (size_t)m0 * NEXP + idx * 4);
        int row = idx >> 2, cq = (idx & 3) * 4;
#pragma unroll
        for (int c = 0; c < 4; c++) cwS[row * 17 + cq + c] = v[c];
    }

    f32x4 acc[4][2];
#pragma unroll
    for (int mt = 0; mt < 4; mt++)
#pragma unroll
        for (int nt = 0; nt < 2; nt++)
#pragma unroll
            for (int r2 = 0; r2 < 4; r2++) acc[mt][nt][r2] = 0.f;

    int mrow[4], nrow[2];
#pragma unroll
    for (int mt = 0; mt < 4; mt++) mrow[mt] = (wm * 64 + mt * 16 + lr) * 64;
#pragma unroll
    for (int nt = 0; nt < 2; nt++) nrow[nt] = (wn * 32 + nt * 16 + lr) * 64;
    int swz = lr & 7;

    const bf16* abase = xt + (size_t)(mblk * 16) * 8192 + t * 8;
    const bf16* bbase = wt + (size_t)(nblk * 256) * 4096 + t * 8;

    for (int ne = 0; ne < NEXP; ne++) {
        f32x4 pacc[4][2];
#pragma unroll
        for (int mt = 0; mt < 4; mt++)
#pragma unroll
            for (int nt = 0; nt < 2; nt++)
#pragma unroll
                for (int r2 = 0; r2 < 4; r2++) pacc[mt][nt][r2] = 0.f;

        for (int ks = 0; ks < 16; ks++) {
            const bf16* asrc = abase + (size_t)ks * 8192;               // A-tile reused across experts
            const bf16* bsrc = bbase + (size_t)(ne * 16 + ks) * 4096;
#pragma unroll
            for (int r = 0; r < 4; r++) gld_lds16(asrc + r * 2048, &As[r * 2048 + t * 8]);
#pragma unroll
            for (int r = 0; r < 2; r++) gld_lds16(bsrc + r * 2048, &Bs[r * 2048 + t * 8]);
            __syncthreads();               // drains vmcnt -> LDS images complete
#pragma unroll
            for (int kk = 0; kk < 2; kk++) {
                int sc8 = ((kk * 4 + lq) ^ swz) * 8;
                bf16x8 af[4], bfr[2];
#pragma unroll
                for (int mt = 0; mt < 4; mt++) af[mt] = *(const bf16x8*)&As[mrow[mt] + sc8];
#pragma unroll
                for (int nt = 0; nt < 2; nt++) bfr[nt] = *(const bf16x8*)&Bs[nrow[nt] + sc8];
#pragma unroll
                for (int mt = 0; mt < 4; mt++)
#pragma unroll
                    for (int nt = 0; nt < 2; nt++)
                        pacc[mt][nt] = __builtin_amdgcn_mfma_f32_16x16x32_bf16(
                            af[mt], bfr[nt], pacc[mt][nt], 0, 0, 0);
            }
            __syncthreads();
        }
        // fold expert partial into master acc with cw scale (row-dependent)
#pragma unroll
        for (int mt = 0; mt < 4; mt++) {
            int rowb = wm * 64 + mt * 16 + lq * 4;
#pragma unroll
            for (int r2 = 0; r2 < 4; r2++) {
                float s = cwS[(rowb + r2) * 17 + ne];
                acc[mt][0][r2] += s * pacc[mt][0][r2];
                acc[mt][1][r2] += s * pacc[mt][1][r2];
            }
        }
    }

    // ---- bias k-step: A = cw (cols 0..15, zero pad), B = bias -> acc ----
    {
        int m_loc = t >> 1;
        const float* cwr = cw + (size_t)(m0 + m_loc) * NEXP;
#pragma unroll
        for (int h = 0; h < 4; h++) {
            int c = (t & 1) * 4 + h;
            bf16x8 v;
#pragma unroll
            for (int j = 0; j < 8; j++) v[j] = (bf16)0.f;
            if (c < 2) {
                f32x4 a = *(const f32x4*)(cwr + c * 8);
                f32x4 b = *(const f32x4*)(cwr + c * 8 + 4);
#pragma unroll
                for (int j = 0; j < 4; j++) { v[j] = (bf16)a[j]; v[4 + j] = (bf16)b[j]; }
            }
            int sc = c ^ (m_loc & 7);
            *(bf16x8*)&As[m_loc * 64 + sc * 8] = v;
        }
        int n_loc = t >> 2;
#pragma unroll
        for (int h = 0; h < 2; h++) {
            int c = (t & 3) * 2 + h;
            bf16x8 v;
#pragma unroll
            for (int j = 0; j < 8; j++) v[j] = (bf16)0.f;
            if (c < 2) {
#pragma unroll
                for (int j = 0; j < 8; j++)
                    v[j] = (bf16)bias[(size_t)(c * 8 + j) * OUT_DIM + n0 + n_loc];
            }
            int sc = c ^ (n_loc & 7);
            *(bf16x8*)&Bs[n_loc * 64 + sc * 8] = v;
        }
        __syncthreads();
        int sc8 = (lq ^ swz) * 8;          // kk=0 only; k=16..31 are zeros
#pragma unroll
        for (int mt = 0; mt < 4; mt++) {
            bf16x8 af = *(const bf16x8*)&As[mrow[mt] + sc8];
#pragma unroll
            for (int nt = 0; nt < 2; nt++) {
                bf16x8 bfr = *(const bf16x8*)&Bs[nrow[nt] + sc8];
                acc[mt][nt] = __builtin_amdgcn_mfma_f32_16x16x32_bf16(af, bfr, acc[mt][nt], 0, 0, 0);
            }
        }
    }

    // epilogue: relu + store (C/D layout: col = lane&15, row = quad*4 + reg)
#pragma unroll
    for (int mt = 0; mt < 4; mt++) {
        int row = m0 + wm * 64 + mt * 16 + lq * 4;
#pragma unroll
        for (int nt = 0; nt < 2; nt++) {
            int col = n0 + wn * 32 + nt * 16 + lr;
#pragma unroll
            for (int r2 = 0; r2 < 4; r2++) {
                float v = acc[mt][nt][r2];
                out[(size_t)(row + r2) * OUT_DIM + col] = v > 0.f ? v : 0.f;
            }
        }
    }
}

// ---------------------------------------------------------------------------
// Insurance fallback if ws_size is too small (slow but correct, fp32 vector).
// ---------------------------------------------------------------------------
__global__ void fallback_kernel(const float* __restrict__ x, const float* __restrict__ cw,
                                const float* __restrict__ W, const float* __restrict__ bias,
                                float* __restrict__ out) {
    int o = blockIdx.x * 256 + threadIdx.x;
    int b = o >> 10, oc = o & 1023;
    const float* xr = x + (size_t)b * IN_DIM;
    float accv = 0.f;
    for (int n = 0; n < NEXP; n++) {
        const float* wr = W + (size_t)n * IN_DIM * OUT_DIM + oc;
        float z = 0.f;
        for (int i = 0; i < IN_DIM; i++) z += xr[i] * wr[(size_t)i * OUT_DIM];
        accv += cw[(size_t)b * NEXP + n] * (z + bias[n * OUT_DIM + oc]);
    }
    out[o] = accv > 0.f ? accv : 0.f;
}

extern "C" void kernel_launch(void* const* d_in, const int* in_sizes, int n_in,
                              void* d_out, int out_size, void* d_ws, size_t ws_size,
                              hipStream_t stream) {
    const float* x    = (const float*)d_in[0];
    const float* cw   = (const float*)d_in[1];
    const float* W    = (const float*)d_in[2];
    const float* bias = (const float*)d_in[3];
    float* out = (float*)d_out;

    const size_t wt_elems = (size_t)KDIM * OUT_DIM;        // 16.7M bf16 = 32 MB
    const size_t xt_elems = (size_t)BATCH * IN_DIM;        // 4.2M bf16 = 8 MB
    if (ws_size < (wt_elems + xt_elems) * sizeof(bf16)) {
        fallback_kernel<<<(BATCH * OUT_DIM) / 256, 256, 0, stream>>>(x, cw, W, bias, out);
        return;
    }
    bf16* wt = (bf16*)d_ws;
    bf16* xt = wt + wt_elems;

    convert_w_tiled<<<4096, 256, 0, stream>>>(W, wt);
    convert_x_tiled<<<512, 256, 0, stream>>>(x, xt);
    moe_gemm<<<dim3(16, 32), 256, 0, stream>>>(cw, bias, xt, wt, out);
}

// Round 2
// 256.221 us; speedup vs baseline: 1.2055x; 1.2055x over previous
//
#include <hip/hip_runtime.h>
#include <hip/hip_bf16.h>
#include <cstdint>

#define BATCH   4096
#define IN_DIM  1024
#define OUT_DIM 1024
#define NEXP    16

typedef __bf16 bf16;
typedef __attribute__((ext_vector_type(8))) __bf16 bf16x8;
typedef __attribute__((ext_vector_type(4))) float  f32x4;

#define AS1 __attribute__((address_space(1)))
#define AS3 __attribute__((address_space(3)))

__device__ __forceinline__ void gld_lds16(const bf16* g, bf16* l) {
    __builtin_amdgcn_global_load_lds((const AS1 void*)g, (AS3 void*)l, 16, 0, 0);
}

// ---------------------------------------------------------------------------
// x fp32 [4096][1024] -> 512 pre-tiled swizzled bf16 images (same as R1).
// Tile (mblk 0..31, ks 0..15) = 128 rows x 64 k = 16 KB. Byte
// f = m_loc*128 + sc*16 holds x[mblk*128+m_loc][ks*64 + (sc^(m_loc&7))*8 + j].
// ---------------------------------------------------------------------------
__global__ void convert_x_tiled(const float* __restrict__ x, bf16* __restrict__ xt) {
    int tile = blockIdx.x;                 // 512
    int mblk = tile >> 4, ks = tile & 15;
    int t = threadIdx.x;
#pragma unroll
    for (int r = 0; r < 4; r++) {
        int q = r * 256 + t;
        int m_loc = q >> 3, sc = q & 7;
        int c = sc ^ (m_loc & 7);
        const float* src = x + (size_t)(mblk * 128 + m_loc) * IN_DIM + ks * 64 + c * 8;
        f32x4 a = *(const f32x4*)src;
        f32x4 b = *(const f32x4*)(src + 4);
        bf16x8 v;
#pragma unroll
        for (int j = 0; j < 4; j++) { v[j] = (bf16)a[j]; v[4 + j] = (bf16)b[j]; }
        *(bf16x8*)(xt + (size_t)tile * 8192 + q * 8) = v;
    }
}

// ---------------------------------------------------------------------------
// weight fp32 [16384][1024] -> fragment-ordered bf16 tiles, 8 KB per
// (nblk, ne, ks). Chunk c = sub*64 + lane, sub = kk*4 + wn*2 + nt, holds
// W[ne*1024+ks*64+kk*32+lq*8+j][nblk*64+wn*32+nt*16+lr] at byte c*16+2j.
// This is exactly the order the GEMM's B-fragment ds_read_b128s consume,
// so staging is linear gld_lds16 and LDS reads are conflict-free.
// ---------------------------------------------------------------------------
__global__ void convert_w_frag(const float* __restrict__ W, bf16* __restrict__ wt) {
    int tile = blockIdx.x;                 // 4096 = (nblk<<8)|(ne<<4)|ks
    int nblk = tile >> 8, ne = (tile >> 4) & 15, ks = tile & 15;
    int t = threadIdx.x;
#pragma unroll
    for (int r = 0; r < 2; r++) {
        int c = r * 256 + t;               // 0..511
        int sub = c >> 6, l = c & 63;
        int lr = l & 15, lq = l >> 4;
        int kk = sub >> 2, wn = (sub >> 1) & 1, nt = sub & 1;
        int kbase = ne * 1024 + ks * 64 + kk * 32 + lq * 8;
        int ng = nblk * 64 + wn * 32 + nt * 16 + lr;
        bf16x8 v;
#pragma unroll
        for (int j = 0; j < 8; j++)
            v[j] = (bf16)W[(size_t)(kbase + j) * OUT_DIM + ng];
        *(bf16x8*)(wt + (size_t)tile * 4096 + c * 8) = v;
    }
}

// ---------------------------------------------------------------------------
// GEMM: ks outer (A staged once, frags in regs), ne inner (B streamed,
// double-buffered, ONE barrier per ne). Per-expert partial folded with
// fp32 scales immediately per (mt,nt) to keep register pressure low.
// Block 128m x 64n, 4 waves (2x2), wave tile 64x32, mfma 16x16x32 bf16.
// ---------------------------------------------------------------------------
__global__ __launch_bounds__(256, 3) void moe_gemm(
        const float* __restrict__ cw, const float* __restrict__ bias,
        const bf16* __restrict__ xt, const bf16* __restrict__ wt,
        float* __restrict__ out) {
    int nblk = blockIdx.x;                 // 16 -> bid%8 clusters nblk per XCD
    int mblk = blockIdx.y;                 // 32
    int m0 = mblk * 128, n0 = nblk * 64;
    int t = threadIdx.x;
    int lane = t & 63, w = t >> 6;
    int wm = w >> 1, wn = w & 1;
    int lq = lane >> 4, lr = lane & 15;

    __shared__ bf16 As[128 * 64];          // 16 KB swizzled A image
    __shared__ bf16 Bs[2][64 * 64];        // 2 x 8 KB fragment-ordered B tiles
    __shared__ float cwT[16 * 132];        // cwT[ne][row], stride 132 (banks)

    // transpose cw panel into LDS once
#pragma unroll
    for (int r = 0; r < 2; r++) {
        int q = r * 256 + t;               // 512 f32x4 = 2048 floats
        f32x4 v = *(const f32x4*)(cw + (size_t)m0 * NEXP + q * 4);
        int row = q >> 2, nb = (q & 3) * 4;
#pragma unroll
        for (int c2 = 0; c2 < 4; c2++) cwT[(nb + c2) * 132 + row] = v[c2];
    }

    const f32x4 fz = {0.f, 0.f, 0.f, 0.f};
    f32x4 acc[4][2];
#pragma unroll
    for (int mt = 0; mt < 4; mt++)
#pragma unroll
        for (int nt = 0; nt < 2; nt++) acc[mt][nt] = fz;

    int swz = lr & 7;
    int mrow[4];
#pragma unroll
    for (int mt = 0; mt < 4; mt++) mrow[mt] = (wm * 64 + mt * 16 + lr) * 64;

    const bf16* abase = xt + (size_t)(mblk * 16) * 8192;
    const bf16* bbase = wt + (size_t)nblk * (16 * 16 * 4096);

    for (int ks = 0; ks < 16; ks++) {
        // stage A tile (16 KB) + first B tile (8 KB); one drain barrier
        const bf16* asrc = abase + (size_t)ks * 8192 + t * 8;
#pragma unroll
        for (int r = 0; r < 4; r++) gld_lds16(asrc + r * 2048, &As[r * 2048 + t * 8]);
        const bf16* b0 = bbase + (size_t)ks * 4096 + t * 8;   // ne = 0
#pragma unroll
        for (int r = 0; r < 2; r++) gld_lds16(b0 + r * 2048, &Bs[0][r * 2048 + t * 8]);
        __syncthreads();

        // A fragments -> registers, reused across all 16 experts
        bf16x8 af[4][2];
#pragma unroll
        for (int kk = 0; kk < 2; kk++)
#pragma unroll
            for (int mt = 0; mt < 4; mt++)
                af[mt][kk] = *(const bf16x8*)&As[mrow[mt] + ((kk * 4 + lq) ^ swz) * 8];

#pragma unroll 2
        for (int ne = 0; ne < NEXP; ne++) {
            int buf = ne & 1;
            if (ne < 15) {                 // prefetch next expert's B tile
                const bf16* bn = bbase + (size_t)((ne + 1) * 16 + ks) * 4096 + t * 8;
#pragma unroll
                for (int r = 0; r < 2; r++)
                    gld_lds16(bn + r * 2048, &Bs[buf ^ 1][r * 2048 + t * 8]);
            }
            // B fragments (linear, conflict-free)
            bf16x8 bfr[2][2];
#pragma unroll
            for (int kk = 0; kk < 2; kk++)
#pragma unroll
                for (int nt = 0; nt < 2; nt++)
                    bfr[kk][nt] = *(const bf16x8*)
                        &Bs[buf][((kk * 2 + wn) * 2 + nt) * 512 + lane * 8];
            // scales for this expert (broadcast within quads)
            f32x4 s[4];
#pragma unroll
            for (int mt = 0; mt < 4; mt++)
                s[mt] = *(const f32x4*)&cwT[ne * 132 + wm * 64 + mt * 16 + lq * 4];
            // MFMA + immediate fold (pacc is 1 live f32x4 per chain)
#pragma unroll
            for (int mt = 0; mt < 4; mt++)
#pragma unroll
                for (int nt = 0; nt < 2; nt++) {
                    f32x4 p = __builtin_amdgcn_mfma_f32_16x16x32_bf16(
                        af[mt][0], bfr[0][nt], fz, 0, 0, 0);
                    p = __builtin_amdgcn_mfma_f32_16x16x32_bf16(
                        af[mt][1], bfr[1][nt], p, 0, 0, 0);
                    acc[mt][nt] += s[mt] * p;   // v_pk_fma_f32 x2
                }
            __syncthreads();               // single barrier per expert
        }
    }

    // ---- bias: one MFMA k-step, operands loaded straight to registers ----
    {
        bf16x8 acw[4];
#pragma unroll
        for (int mt = 0; mt < 4; mt++) {
            bf16x8 v;
#pragma unroll
            for (int j = 0; j < 8; j++) v[j] = (bf16)0.f;
            if (lq < 2) {                  // k = lq*8+j in 0..15 real, else 0
                int row = m0 + wm * 64 + mt * 16 + lr;
                f32x4 a = *(const f32x4*)(cw + (size_t)row * NEXP + lq * 8);
                f32x4 b = *(const f32x4*)(cw + (size_t)row * NEXP + lq * 8 + 4);
#pragma unroll
                for (int j = 0; j < 4; j++) { v[j] = (bf16)a[j]; v[4 + j] = (bf16)b[j]; }
            }
            acw[mt] = v;
        }
        bf16x8 bb[2];
#pragma unroll
        for (int nt = 0; nt < 2; nt++) {
            bf16x8 v;
#pragma unroll
            for (int j = 0; j < 8; j++) v[j] = (bf16)0.f;
            if (lq < 2) {
                int col = n0 + wn * 32 + nt * 16 + lr;
#pragma unroll
                for (int j = 0; j < 8; j++)
                    v[j] = (bf16)bias[(size_t)(lq * 8 + j) * OUT_DIM + col];
            }
            bb[nt] = v;
        }
#pragma unroll
        for (int mt = 0; mt < 4; mt++)
#pragma unroll
            for (int nt = 0; nt < 2; nt++)
                acc[mt][nt] = __builtin_amdgcn_mfma_f32_16x16x32_bf16(
                    acw[mt], bb[nt], acc[mt][nt], 0, 0, 0);
    }

    // epilogue: relu + store (C/D: col = lane&15, row = quad*4 + reg)
#pragma unroll
    for (int mt = 0; mt < 4; mt++) {
        int row = m0 + wm * 64 + mt * 16 + lq * 4;
#pragma unroll
        for (int nt = 0; nt < 2; nt++) {
            int col = n0 + wn * 32 + nt * 16 + lr;
#pragma unroll
            for (int r2 = 0; r2 < 4; r2++) {
                float v = acc[mt][nt][r2];
                out[(size_t)(row + r2) * OUT_DIM + col] = v > 0.f ? v : 0.f;
            }
        }
    }
}

// ---------------------------------------------------------------------------
// Insurance fallback if ws_size is too small.
// ---------------------------------------------------------------------------
__global__ void fallback_kernel(const float* __restrict__ x, const float* __restrict__ cw,
                                const float* __restrict__ W, const float* __restrict__ bias,
                                float* __restrict__ out) {
    int o = blockIdx.x * 256 + threadIdx.x;
    int b = o >> 10, oc = o & 1023;
    const float* xr = x + (size_t)b * IN_DIM;
    float accv = 0.f;
    for (int n = 0; n < NEXP; n++) {
        const float* wr = W + (size_t)n * IN_DIM * OUT_DIM + oc;
        float z = 0.f;
        for (int i = 0; i < IN_DIM; i++) z += xr[i] * wr[(size_t)i * OUT_DIM];
        accv += cw[(size_t)b * NEXP + n] * (z + bias[n * OUT_DIM + oc]);
    }
    out[o] = accv > 0.f ? accv : 0.f;
}

extern "C" void kernel_launch(void* const* d_in, const int* in_sizes, int n_in,
                              void* d_out, int out_size, void* d_ws, size_t ws_size,
                              hipStream_t stream) {
    const float* x    = (const float*)d_in[0];
    const float* cw   = (const float*)d_in[1];
    const float* W    = (const float*)d_in[2];
    const float* bias = (const float*)d_in[3];
    float* out = (float*)d_out;

    const size_t wt_elems = (size_t)NEXP * IN_DIM * OUT_DIM;   // 32 MB bf16
    const size_t xt_elems = (size_t)BATCH * IN_DIM;            // 8 MB bf16
    if (ws_size < (wt_elems + xt_elems) * sizeof(bf16)) {
        fallback_kernel<<<(BATCH * OUT_DIM) / 256, 256, 0, stream>>>(x, cw, W, bias, out);
        return;
    }
    bf16* wt = (bf16*)d_ws;
    bf16* xt = wt + wt_elems;

    convert_w_frag<<<4096, 256, 0, stream>>>(W, wt);
    convert_x_tiled<<<512, 256, 0, stream>>>(x, xt);
    moe_gemm<<<dim3(16, 32), 256, 0, stream>>>(cw, bias, xt, wt, out);
}